// Round 1
// 231.519 us; speedup vs baseline: 1.5564x; 1.5564x over previous
//
#include <hip/hip_runtime.h>

// Conv2d + BN int8 quantized, MI355X gfx950. Inputs fp32, output fp32.
// R6: conv was latency-bound (MfmaUtil 12%, VALUBusy 14%, Occ 22%): 50KB of LDS
// held WEIGHTS (re-staged from L2 by all 3584 blocks behind 6 barriers/block).
// This round:
//   quant_w_kernel: packs int8 weights in per-lane MFMA fragment order
//       qwfL[((((og*3+kh)*3+kw)*4+c04)*2+t)*64 + l16*4+quad], og = o>>5,
//       so conv reads A-operands directly from L2 as coalesced 8B/lane loads.
//   conv_kernel:    LDS holds only 3 x-rows (26.9KB). ONE barrier per block,
//       then 288 MFMAs with streamed A-loads. __launch_bounds__(256,4) -> 4 blk/CU.
// Host falls back to the proven R5 fused kernel if ws_size is too small.

#define BATCH 32
#define CIN   128
#define HH    56
#define WW    56
#define OCH   256

typedef __attribute__((ext_vector_type(4))) int int4v;

#define QX_BYTES (32 * 32 * 56 * 56 * 4)        // 12,845,056
#define QW_BYTES (256 * 1152)                   // 294,912 (fragment-packed)
#define WS_NEEDED (QX_BYTES + QW_BYTES + 1024)

// ---------------- kernel 1: weight quantization + fragment pack ------------
// One block per og (32 output channels). Packs so that conv lane (l16,quad)
// of wave 'wave' reads long index
//   (((( (blockIdx.y*4+wave)*3 + kh)*3 + kw)*4 + c04)*2 + t)*64 + l16*4+quad
// holding channels c04*32+quad*8..+7 of output row og*32+t*16+l16 at (kh,kw).
__global__ __launch_bounds__(256) void quant_w_kernel(
    const float* __restrict__ w, const float* __restrict__ sxp,
    char* __restrict__ qwf, float* __restrict__ alpha) {
  __shared__ float scaleS[32];
  __shared__ __attribute__((aligned(16))) char buf[36864];
  const int og = blockIdx.x;          // 0..7
  const int tid = threadIdx.x;
  const int ol = tid >> 3, part = tid & 7;   // 8 threads per output row
  const int o = og * 32 + ol;
  const float* wrow = w + (size_t)o * 1152;
  // per-o absmax: part covers channels part*16..part*16+15 (144 floats)
  float m = 0.f;
  const float4* p4 = (const float4*)(wrow + part * 144);
#pragma unroll 4
  for (int i = 0; i < 36; ++i) {
    const float4 v = p4[i];
    m = fmaxf(m, fmaxf(fmaxf(fabsf(v.x), fabsf(v.y)),
                       fmaxf(fabsf(v.z), fabsf(v.w))));
  }
  m = fmaxf(m, __shfl_down(m, 4));
  m = fmaxf(m, __shfl_down(m, 2));
  m = fmaxf(m, __shfl_down(m, 1));
  if (part == 0) {
    const float sc = m / 127.0f;   // max/QMAX, fp32, matches reference
    scaleS[ol] = sc;
    alpha[o] = sc * sxp[0];
  }
  __syncthreads();
  const float sc = scaleS[ol];
  const int t = ol >> 4, l16 = ol & 15;
  for (int cc = 0; cc < 16; ++cc) {
    const int c = part * 16 + cc;
    const int c04 = c >> 5, quad = (c >> 3) & 3, j = c & 7;
    const int lanoff = (l16 * 4 + quad) * 8 + j;
#pragma unroll
    for (int r = 0; r < 9; ++r) {   // r = kh*3 + kw ; w layout [O][C][3][3]
      const float q = fminf(127.f, fmaxf(-127.f, rintf(wrow[c * 9 + r] / sc)));
      buf[((r * 4 + c04) * 2 + t) * 512 + lanoff] = (char)(int)q;
    }
  }
  __syncthreads();
  long* dst = (long*)(qwf + (size_t)og * 36864);
  const long* src = (const long*)buf;
  for (int i = tid; i < 4608; i += 256) dst[i] = src[i];  // coalesced copyout
}

// ---------------- kernel 2: x quantization, channel-packed -----------------
// qxT dword index: (b*32 + c4)*3136 + h*56 + w ; byte k = channel c4*4+k.
__global__ __launch_bounds__(256) void quant_x_kernel(
    const float* __restrict__ x, const float* __restrict__ sxp,
    unsigned int* __restrict__ qx4) {
  const int row = blockIdx.x;  // b*56 + h
  const int b = row / 56, h = row % 56;
  const float sx = sxp[0];
  for (int i = threadIdx.x; i < 1792; i += 256) {
    const int c4 = i / 56, w = i % 56;
    unsigned int pack = 0;
#pragma unroll
    for (int k = 0; k < 4; ++k) {
      const float xv = x[(((size_t)b * 128 + c4 * 4 + k) * 56 + h) * 56 + w];
      const int q = (int)fminf(127.f, fmaxf(-127.f, rintf(xv / sx)));
      pack |= ((unsigned int)(q & 255)) << (8 * k);
    }
    qx4[((size_t)b * 32 + c4) * 3136 + h * 56 + w] = pack;
  }
}

// ---------------- kernel 3: conv (i8 MFMA, weights from L2) ----------------
#define XROW  136                 // 128 int8 + 8 pad (8B aligned)
#define XSLAB (66 * XROW)         // 8976 per input row
#define XDW   34                  // dwords per row

__global__ __launch_bounds__(256, 4) void conv_kernel(
    const unsigned int* __restrict__ qx4, const char* __restrict__ qwf,
    const float* __restrict__ alpha, const float* __restrict__ bias,
    float* __restrict__ out) {
  __shared__ __attribute__((aligned(16))) char Xs8[3 * XSLAB];  // 26,928 B

  const int bi = blockIdx.x;
  const int b  = bi / 56;
  const int oh = bi % 56;
  const int o0 = blockIdx.y * 128;
  const int tid = threadIdx.x;
  const int wave = tid >> 6, lane = tid & 63;
  const int l16 = lane & 15, quad = lane >> 4;

  // in-block MFMA C/D layout probe (verified working since R5)
  int m_r[4], n_r[4];
  {
    int4v zz = {0, 0, 0, 0};
    long a1 = 0, b1 = 0, a2 = 0, b2 = 0;
    if (quad == 0) {
      a1 = 1L;               // A = delta(k=0)
      b1 = (long)(l16 + 1);  // B[0][n] = n+1
      a2 = (long)(l16 + 1);  // A[m][0] = m+1
      b2 = 1L;               // B = delta(k=0)
    }
    int4v d1 = __builtin_amdgcn_mfma_i32_16x16x32_i8(a1, b1, zz, 0, 0, 0);
    int4v d2 = __builtin_amdgcn_mfma_i32_16x16x32_i8(a2, b2, zz, 0, 0, 0);
#pragma unroll
    for (int r = 0; r < 4; ++r) {
      n_r[r] = (d1[r] - 1) & 15;
      m_r[r] = (d2[r] - 1) & 15;
    }
  }

  // ---- stage ALL 3 input rows (the only LDS use), then ONE barrier ----
  const size_t srcb = (size_t)b * 32 * 3136;
  for (int kh = 0; kh < 3; ++kh) {
    const int ih = oh - 1 + kh;
    unsigned int* Xd = (unsigned int*)(Xs8 + kh * XSLAB);
    if (ih >= 0 && ih < HH) {
      for (int i = tid; i < 1792; i += 256) {       // coalesced 224B per c4
        const int c4 = i / 56, col = i - c4 * 56 + 1;  // col = iw+1
        Xd[col * XDW + c4] = qx4[srcb + (size_t)c4 * 3136 + ih * 56 + col - 1];
      }
      for (int i = tid; i < 340; i += 256) {        // zero cols {0, 57..65}
        const int r = i / XDW, dw = i - r * XDW;
        const int col = (r == 0) ? 0 : 56 + r;
        Xd[col * XDW + dw] = 0u;
      }
    } else {
      for (int i = tid; i < 66 * XDW; i += 256) Xd[i] = 0u;
    }
  }

  int4v acc[2][4];
#pragma unroll
  for (int t = 0; t < 2; ++t)
#pragma unroll
    for (int u = 0; u < 4; ++u) acc[t][u] = (int4v){0, 0, 0, 0};

  __syncthreads();

  // A-operands streamed straight from L2, fragment-packed & coalesced.
  const long* wbase = (const long*)qwf +
      (size_t)(blockIdx.y * 4 + wave) * 4608 + (l16 * 4 + quad);

#pragma unroll
  for (int kh = 0; kh < 3; ++kh) {
    const char* Xk = Xs8 + kh * XSLAB;
#pragma unroll
    for (int kw = 0; kw < 3; ++kw) {
#pragma unroll
      for (int c04 = 0; c04 < 4; ++c04) {
        const int fi = ((kh * 3 + kw) * 4 + c04) * 2;
        const long aop0 = wbase[(size_t)fi * 64];
        const long aop1 = wbase[(size_t)fi * 64 + 64];
        long bop[4];
#pragma unroll
        for (int u = 0; u < 4; ++u)
          bop[u] = *(const long*)(Xk + (u * 16 + l16 + kw) * XROW +
                                  c04 * 32 + quad * 8);
#pragma unroll
        for (int u = 0; u < 4; ++u) {
          acc[0][u] = __builtin_amdgcn_mfma_i32_16x16x32_i8(
              aop0, bop[u], acc[0][u], 0, 0, 0);
          acc[1][u] = __builtin_amdgcn_mfma_i32_16x16x32_i8(
              aop1, bop[u], acc[1][u], 0, 0, 0);
        }
      }
    }
  }

#pragma unroll
  for (int t = 0; t < 2; ++t) {
#pragma unroll
    for (int u = 0; u < 4; ++u) {
#pragma unroll
      for (int r = 0; r < 4; ++r) {
        const int ol = wave * 32 + t * 16 + m_r[r];
        const int ow = u * 16 + n_r[r];
        if (ow < WW) {
          const int oo = o0 + ol;
          out[(((size_t)b * OCH + oo) * HH + oh) * WW + ow] =
              (float)acc[t][u][r] * alpha[oo] + bias[oo];
        }
      }
    }
  }
}

// ---------------- fallback: R5's proven fused kernel (ws-free) -------------
#define FAS_ROW 392
#define FXS_ROW 136
#define FLDS_XS (128 * FAS_ROW)
#define FLDS_SC (FLDS_XS + 66 * FXS_ROW)
#define FLDS_AL (FLDS_SC + 512)
#define FLDS_BI (FLDS_AL + 512)
#define FLDS_RED (FLDS_BI + 512)
#define FLDS_TOT (FLDS_RED + 1024)

__global__ __launch_bounds__(256) void conv_fused_kernel(
    const float* __restrict__ x, const float* __restrict__ w,
    const float* __restrict__ bias, const float* __restrict__ sxp,
    float* __restrict__ out) {
  __shared__ __attribute__((aligned(16))) char lds[FLDS_TOT];
  char* As8 = lds;
  char* Xs8 = lds + FLDS_XS;
  float* scaleS = (float*)(lds + FLDS_SC);
  float* alphaS = (float*)(lds + FLDS_AL);
  float* biasS  = (float*)(lds + FLDS_BI);
  float* red    = (float*)(lds + FLDS_RED);

  const int bi = blockIdx.x;
  const int b  = bi / 56;
  const int oh = bi % 56;
  const int o0 = blockIdx.y * 128;
  const int tid = threadIdx.x;
  const int wave = tid >> 6, lane = tid & 63;
  const int l16 = lane & 15, quad = lane >> 4;
  const float sx = sxp[0];

  int m_r[4], n_r[4];
  {
    int4v zz = {0, 0, 0, 0};
    long a1 = 0, b1 = 0, a2 = 0, b2 = 0;
    if (quad == 0) { a1 = 1L; b1 = (long)(l16 + 1); a2 = (long)(l16 + 1); b2 = 1L; }
    int4v d1 = __builtin_amdgcn_mfma_i32_16x16x32_i8(a1, b1, zz, 0, 0, 0);
    int4v d2 = __builtin_amdgcn_mfma_i32_16x16x32_i8(a2, b2, zz, 0, 0, 0);
#pragma unroll
    for (int r = 0; r < 4; ++r) { n_r[r] = (d1[r] - 1) & 15; m_r[r] = (d2[r] - 1) & 15; }
  }
  {
    const int o = tid >> 1, half = tid & 1;
    const float4* p = (const float4*)(w + (size_t)(o0 + o) * 1152 + half * 576);
    float m = 0.f;
#pragma unroll 4
    for (int i = 0; i < 144; ++i) {
      const float4 v = p[i];
      m = fmaxf(m, fmaxf(fmaxf(fabsf(v.x), fabsf(v.y)), fmaxf(fabsf(v.z), fabsf(v.w))));
    }
    red[tid] = m;
  }
  __syncthreads();
  {
    const int o = tid >> 1;
    if ((tid & 1) == 0) {
      const float sc = fmaxf(red[2 * o], red[2 * o + 1]) / 127.0f;
      scaleS[o] = sc; alphaS[o] = sc * sx; biasS[o] = bias[o0 + o];
    }
  }
  int4v acc[2][4];
#pragma unroll
  for (int t = 0; t < 2; ++t)
#pragma unroll
    for (int u = 0; u < 4; ++u) acc[t][u] = (int4v){0, 0, 0, 0};

  for (int kh = 0; kh < 3; ++kh) {
    const int ih = oh - 1 + kh;
    const bool row_ok = (ih >= 0) && (ih < HH);
    __syncthreads();
    for (int idx = tid; idx < 66 * 128; idx += 256) {
      const int col = idx % 66, c = idx / 66, iw = col - 1;
      int q = 0;
      if (row_ok && iw >= 0 && iw < WW) {
        const float xv = x[(((size_t)b * CIN + c) * HH + ih) * WW + iw];
        q = (int)fminf(127.f, fmaxf(-127.f, rintf(xv / sx)));
      }
      Xs8[col * FXS_ROW + c] = (char)q;
    }
    for (int idx = tid; idx < 16384; idx += 256) {
      const int c = idx & 127, o = idx >> 7;
      const float s = scaleS[o];
      const float* wp = w + (size_t)(o0 + o) * 1152 + c * 9 + kh * 3;
#pragma unroll
      for (int kw = 0; kw < 3; ++kw) {
        const int q = (int)fminf(127.f, fmaxf(-127.f, rintf(wp[kw] / s)));
        As8[o * FAS_ROW + kw * 128 + c] = (char)q;
      }
    }
    __syncthreads();
    const int obase = wave * 32;
#pragma unroll
    for (int kw = 0; kw < 3; ++kw) {
#pragma unroll
      for (int c0 = 0; c0 < 128; c0 += 32) {
        long aop[2], bop[4];
#pragma unroll
        for (int t = 0; t < 2; ++t)
          aop[t] = *(const long*)(As8 + (obase + t * 16 + l16) * FAS_ROW + kw * 128 + c0 + quad * 8);
#pragma unroll
        for (int u = 0; u < 4; ++u)
          bop[u] = *(const long*)(Xs8 + (u * 16 + l16 + kw) * FXS_ROW + c0 + quad * 8);
#pragma unroll
        for (int t = 0; t < 2; ++t)
#pragma unroll
          for (int u = 0; u < 4; ++u)
            acc[t][u] = __builtin_amdgcn_mfma_i32_16x16x32_i8(aop[t], bop[u], acc[t][u], 0, 0, 0);
      }
    }
  }
#pragma unroll
  for (int t = 0; t < 2; ++t) {
#pragma unroll
    for (int u = 0; u < 4; ++u) {
#pragma unroll
      for (int r = 0; r < 4; ++r) {
        const int ol = wave * 32 + t * 16 + m_r[r];
        const int ow = u * 16 + n_r[r];
        if (ow < WW)
          out[(((size_t)b * OCH + o0 + ol) * HH + oh) * WW + ow] =
              (float)acc[t][u][r] * alphaS[ol] + biasS[ol];
      }
    }
  }
}

extern "C" void kernel_launch(void* const* d_in, const int* in_sizes, int n_in,
                              void* d_out, int out_size, void* d_ws, size_t ws_size,
                              hipStream_t stream) {
  const float *x = nullptr, *w = nullptr, *bias = nullptr, *sx = nullptr;
  for (int i = 0; i < n_in; ++i) {
    const int s = in_sizes[i];
    if (s == BATCH * CIN * HH * WW) x = (const float*)d_in[i];
    else if (s == OCH * CIN * 9)    w = (const float*)d_in[i];
    else if (s == OCH)              bias = (const float*)d_in[i];
    else if (s == 1)                sx = (const float*)d_in[i];
  }
  if (!x || !w || !bias || !sx) {
    x = (const float*)d_in[0]; w = (const float*)d_in[1];
    bias = (const float*)d_in[2]; sx = (const float*)d_in[3];
  }
  float* out = (float*)d_out;

  if (ws_size >= (size_t)WS_NEEDED) {
    unsigned int* qx4 = (unsigned int*)d_ws;
    char* qw = (char*)d_ws + QX_BYTES;
    float* alpha = (float*)((char*)d_ws + QX_BYTES + QW_BYTES);
    quant_w_kernel<<<8, 256, 0, stream>>>(w, sx, qw, alpha);
    quant_x_kernel<<<BATCH * HH, 256, 0, stream>>>(x, sx, qx4);
    conv_kernel<<<dim3(BATCH * HH, 2), 256, 0, stream>>>(qx4, qw, alpha, bias, out);
  } else {
    conv_fused_kernel<<<dim3(BATCH * HH, 2), 256, 0, stream>>>(x, w, bias, sx, out);
  }
}

// Round 2
// 225.121 us; speedup vs baseline: 1.6006x; 1.0284x over previous
//
#include <hip/hip_runtime.h>

// Conv2d + BN int8 quantized, MI355X gfx950. Inputs fp32, output fp32.
// R7: conv was still latency-bound (MfmaUtil 33, VALU 27, Occ 46). Changes:
//   quant_x_kernel: emits im2col row layout qxp[b][h][w][128c] int8 (12.8MB,
//       same ws budget), with the LDS bank-swizzle PRE-APPLIED at store time:
//       byte j of row w holds channel j ^ (((w+1)&7)<<4)  (T2 both-sides rule).
//   conv_kernel: staging = 3 contiguous 7168B global_load_lds(width=16) copies
//       + small zero fills. LDS 25344B -> 6 blocks/CU (launch_bounds(256,6)).
//       B-operand ds_read_b64 at boff ^ ((l16+kw)&7)<<4 — conflict-free
//       (wave's 128 dword-accesses land exactly 4/bank = minimum).
//   quant_w_kernel: 256 blocks (one per o), LDS-staged, coalesced absmax;
//       same fragment-packed output format as R6 (verified passing).
// Host falls back to the proven R5 fused kernel if ws_size is too small.

#define BATCH 32
#define CIN   128
#define HH    56
#define WW    56
#define OCH   256

typedef __attribute__((ext_vector_type(4))) int int4v;

#define QX_BYTES (32 * 56 * 56 * 128)           // 12,845,056  qxp[b][h][w][c]
#define QW_BYTES (256 * 1152)                   // 294,912 (fragment-packed)
#define WS_NEEDED (QX_BYTES + QW_BYTES + 1024)

__device__ __forceinline__ void gload_lds16(const void* g, void* l) {
  __builtin_amdgcn_global_load_lds(
      (const __attribute__((address_space(1))) unsigned int*)g,
      (__attribute__((address_space(3))) unsigned int*)l, 16, 0, 0);
}

// ---------------- kernel 1: weight quantization + fragment pack ------------
// One block per output channel o. Output long index (same format as R6):
//   qwfL[og*4608 + ((r*4+c04)*2+t)*64 + l16*4+quad], og=o>>5, t=(o>>4)&1,
//   l16=o&15, holding channels c04*32+quad*8..+7 at tap r = kh*3+kw.
__global__ __launch_bounds__(256) void quant_w_kernel(
    const float* __restrict__ w, const float* __restrict__ sxp,
    char* __restrict__ qwf, float* __restrict__ alpha) {
  __shared__ float wf[1152];
  __shared__ float red[256];
  const int o = blockIdx.x;
  const int tid = threadIdx.x;
  const float* wrow = w + (size_t)o * 1152;
  float m = 0.f;
  for (int i = tid; i < 288; i += 256) {
    const float4 v = ((const float4*)wrow)[i];
    ((float4*)wf)[i] = v;
    m = fmaxf(m, fmaxf(fmaxf(fabsf(v.x), fabsf(v.y)),
                       fmaxf(fabsf(v.z), fabsf(v.w))));
  }
  red[tid] = m;
  __syncthreads();
  for (int s = 128; s > 0; s >>= 1) {
    if (tid < s) red[tid] = fmaxf(red[tid], red[tid + s]);
    __syncthreads();
  }
  const float sc = red[0] / 127.0f;   // max/QMAX, fp32, matches reference
  if (tid == 0) alpha[o] = sc * sxp[0];
  if (tid < 36) {
    const int r = tid >> 2, c04 = tid & 3;
    const int og = o >> 5, t = (o >> 4) & 1, l16 = o & 15;
    unsigned int* dst = (unsigned int*)(qwf + (size_t)og * 36864 +
                                        ((r * 4 + c04) * 2 + t) * 512 + l16 * 32);
#pragma unroll
    for (int g = 0; g < 8; ++g) {
      unsigned int pk = 0;
#pragma unroll
      for (int k = 0; k < 4; ++k) {
        const int c = c04 * 32 + g * 4 + k;
        const int q = (int)fminf(127.f, fmaxf(-127.f, rintf(wf[c * 9 + r] / sc)));
        pk |= ((unsigned int)(q & 255)) << (8 * k);
      }
      dst[g] = pk;
    }
  }
}

// ---------------- kernel 2: x quantization -> swizzled im2col rows ---------
// qxp byte ((b*56+h)*56 + w)*128 + j holds q(x[b][ j^(((w+1)&7)<<4) ][h][w]).
__global__ __launch_bounds__(256) void quant_x_kernel(
    const float* __restrict__ x, const float* __restrict__ sxp,
    unsigned int* __restrict__ qxp) {
  __shared__ char ldsA[128 * 60];   // [c][w] quantized bytes, stride 60
  const int row = blockIdx.x;       // b*56 + h
  const int b = row / 56, h = row % 56;
  const float sx = sxp[0];
  for (int i = threadIdx.x; i < 1792; i += 256) {
    const int c = i / 14, f = i % 14;
    const float4 v =
        *(const float4*)(x + (((size_t)b * 128 + c) * 56 + h) * 56 + 4 * f);
    unsigned int pk;
    pk  = (unsigned int)((int)fminf(127.f, fmaxf(-127.f, rintf(v.x / sx))) & 255);
    pk |= ((unsigned int)((int)fminf(127.f, fmaxf(-127.f, rintf(v.y / sx))) & 255)) << 8;
    pk |= ((unsigned int)((int)fminf(127.f, fmaxf(-127.f, rintf(v.z / sx))) & 255)) << 16;
    pk |= ((unsigned int)((int)fminf(127.f, fmaxf(-127.f, rintf(v.w / sx))) & 255)) << 24;
    *(unsigned int*)(ldsA + c * 60 + 4 * f) = pk;
  }
  __syncthreads();
  unsigned int* orow = qxp + (size_t)row * 56 * 32;
  for (int i = threadIdx.x; i < 1792; i += 256) {
    const int w = i >> 5, jd = i & 31;
    const int c0 = (jd ^ (((w + 1) & 7) << 2)) << 2;  // channel base (4-run)
    unsigned int pk = 0;
#pragma unroll
    for (int k = 0; k < 4; ++k)
      pk |= ((unsigned int)(unsigned char)ldsA[(c0 + k) * 60 + w]) << (8 * k);
    orow[i] = pk;
  }
}

// ---------------- kernel 3: conv (i8 MFMA, weights from L2) ----------------
#define XSLAB 8448                  // 66 cols * 128B, contiguous (no pad)

__global__ __launch_bounds__(256, 6) void conv_kernel(
    const char* __restrict__ qxp, const char* __restrict__ qwf,
    const float* __restrict__ alpha, const float* __restrict__ bias,
    float* __restrict__ out) {
  __shared__ __attribute__((aligned(16))) char Xs8[3 * XSLAB];  // 25,344 B

  const int bi = blockIdx.x;
  const int b  = bi / 56;
  const int oh = bi % 56;
  const int o0 = blockIdx.y * 128;
  const int tid = threadIdx.x;
  const int wave = tid >> 6, lane = tid & 63;
  const int l16 = lane & 15, quad = lane >> 4;

  // in-block MFMA C/D layout probe (verified working since R5)
  int m_r[4], n_r[4];
  {
    int4v zz = {0, 0, 0, 0};
    long a1 = 0, b1 = 0, a2 = 0, b2 = 0;
    if (quad == 0) {
      a1 = 1L;               // A = delta(k=0)
      b1 = (long)(l16 + 1);  // B[0][n] = n+1
      a2 = (long)(l16 + 1);  // A[m][0] = m+1
      b2 = 1L;               // B = delta(k=0)
    }
    int4v d1 = __builtin_amdgcn_mfma_i32_16x16x32_i8(a1, b1, zz, 0, 0, 0);
    int4v d2 = __builtin_amdgcn_mfma_i32_16x16x32_i8(a2, b2, zz, 0, 0, 0);
#pragma unroll
    for (int r = 0; r < 4; ++r) {
      n_r[r] = (d1[r] - 1) & 15;
      m_r[r] = (d2[r] - 1) & 15;
    }
  }

  // ---- stage 3 input rows: contiguous async copies + small zero fills ----
  for (int kh = 0; kh < 3; ++kh) {
    const int ih = oh - 1 + kh;
    char* slab = Xs8 + kh * XSLAB;
    if (ih >= 0 && ih < HH) {
      const char* src = qxp + ((size_t)b * 56 + ih) * 7168;
      for (int i = tid; i < 448; i += 256)
        gload_lds16(src + i * 16, slab + 128 + i * 16);   // cols 1..56
      for (int i = tid; i < 320; i += 256) {              // zero cols 0,57..65
        const int cg = i >> 5, dw = i & 31;
        const int col = (cg == 0) ? 0 : 56 + cg;
        ((unsigned int*)slab)[col * 32 + dw] = 0u;
      }
    } else {
      for (int i = tid; i < 2112; i += 256) ((unsigned int*)slab)[i] = 0u;
    }
  }

  int4v acc[2][4];
#pragma unroll
  for (int t = 0; t < 2; ++t)
#pragma unroll
    for (int u = 0; u < 4; ++u) acc[t][u] = (int4v){0, 0, 0, 0};

  __syncthreads();   // drains vmcnt (global_load_lds) + lgkm (zero stores)

  // A-operands streamed straight from L2, fragment-packed & coalesced.
  const long* wbase = (const long*)qwf +
      (size_t)(blockIdx.y * 4 + wave) * 4608 + (l16 * 4 + quad);

#pragma unroll
  for (int kh = 0; kh < 3; ++kh) {
    const char* Xk = Xs8 + kh * XSLAB;
#pragma unroll
    for (int kw = 0; kw < 3; ++kw) {
      const int ph = ((l16 + kw) & 7) << 4;   // row-phase, u-invariant
#pragma unroll
      for (int c04 = 0; c04 < 4; ++c04) {
        const int fi = ((kh * 3 + kw) * 4 + c04) * 2;
        const long aop0 = wbase[(size_t)fi * 64];
        const long aop1 = wbase[(size_t)fi * 64 + 64];
        const int boff = (c04 * 32 + quad * 8) ^ ph;
        long bop[4];
#pragma unroll
        for (int u = 0; u < 4; ++u)
          bop[u] = *(const long*)(Xk + (u * 16 + l16 + kw) * 128 + boff);
#pragma unroll
        for (int u = 0; u < 4; ++u) {
          acc[0][u] = __builtin_amdgcn_mfma_i32_16x16x32_i8(
              aop0, bop[u], acc[0][u], 0, 0, 0);
          acc[1][u] = __builtin_amdgcn_mfma_i32_16x16x32_i8(
              aop1, bop[u], acc[1][u], 0, 0, 0);
        }
      }
    }
  }

#pragma unroll
  for (int t = 0; t < 2; ++t) {
#pragma unroll
    for (int u = 0; u < 4; ++u) {
#pragma unroll
      for (int r = 0; r < 4; ++r) {
        const int ol = wave * 32 + t * 16 + m_r[r];
        const int ow = u * 16 + n_r[r];
        if (ow < WW) {
          const int oo = o0 + ol;
          out[(((size_t)b * OCH + oo) * HH + oh) * WW + ow] =
              (float)acc[t][u][r] * alpha[oo] + bias[oo];
        }
      }
    }
  }
}

// ---------------- fallback: R5's proven fused kernel (ws-free) -------------
#define FAS_ROW 392
#define FXS_ROW 136
#define FLDS_XS (128 * FAS_ROW)
#define FLDS_SC (FLDS_XS + 66 * FXS_ROW)
#define FLDS_AL (FLDS_SC + 512)
#define FLDS_BI (FLDS_AL + 512)
#define FLDS_RED (FLDS_BI + 512)
#define FLDS_TOT (FLDS_RED + 1024)

__global__ __launch_bounds__(256) void conv_fused_kernel(
    const float* __restrict__ x, const float* __restrict__ w,
    const float* __restrict__ bias, const float* __restrict__ sxp,
    float* __restrict__ out) {
  __shared__ __attribute__((aligned(16))) char lds[FLDS_TOT];
  char* As8 = lds;
  char* Xs8 = lds + FLDS_XS;
  float* scaleS = (float*)(lds + FLDS_SC);
  float* alphaS = (float*)(lds + FLDS_AL);
  float* biasS  = (float*)(lds + FLDS_BI);
  float* red    = (float*)(lds + FLDS_RED);

  const int bi = blockIdx.x;
  const int b  = bi / 56;
  const int oh = bi % 56;
  const int o0 = blockIdx.y * 128;
  const int tid = threadIdx.x;
  const int wave = tid >> 6, lane = tid & 63;
  const int l16 = lane & 15, quad = lane >> 4;
  const float sx = sxp[0];

  int m_r[4], n_r[4];
  {
    int4v zz = {0, 0, 0, 0};
    long a1 = 0, b1 = 0, a2 = 0, b2 = 0;
    if (quad == 0) { a1 = 1L; b1 = (long)(l16 + 1); a2 = (long)(l16 + 1); b2 = 1L; }
    int4v d1 = __builtin_amdgcn_mfma_i32_16x16x32_i8(a1, b1, zz, 0, 0, 0);
    int4v d2 = __builtin_amdgcn_mfma_i32_16x16x32_i8(a2, b2, zz, 0, 0, 0);
#pragma unroll
    for (int r = 0; r < 4; ++r) { n_r[r] = (d1[r] - 1) & 15; m_r[r] = (d2[r] - 1) & 15; }
  }
  {
    const int o = tid >> 1, half = tid & 1;
    const float4* p = (const float4*)(w + (size_t)(o0 + o) * 1152 + half * 576);
    float m = 0.f;
#pragma unroll 4
    for (int i = 0; i < 144; ++i) {
      const float4 v = p[i];
      m = fmaxf(m, fmaxf(fmaxf(fabsf(v.x), fabsf(v.y)), fmaxf(fabsf(v.z), fabsf(v.w))));
    }
    red[tid] = m;
  }
  __syncthreads();
  {
    const int o = tid >> 1;
    if ((tid & 1) == 0) {
      const float sc = fmaxf(red[2 * o], red[2 * o + 1]) / 127.0f;
      scaleS[o] = sc; alphaS[o] = sc * sx; biasS[o] = bias[o0 + o];
    }
  }
  int4v acc[2][4];
#pragma unroll
  for (int t = 0; t < 2; ++t)
#pragma unroll
    for (int u = 0; u < 4; ++u) acc[t][u] = (int4v){0, 0, 0, 0};

  for (int kh = 0; kh < 3; ++kh) {
    const int ih = oh - 1 + kh;
    const bool row_ok = (ih >= 0) && (ih < HH);
    __syncthreads();
    for (int idx = tid; idx < 66 * 128; idx += 256) {
      const int col = idx % 66, c = idx / 66, iw = col - 1;
      int q = 0;
      if (row_ok && iw >= 0 && iw < WW) {
        const float xv = x[(((size_t)b * CIN + c) * HH + ih) * WW + iw];
        q = (int)fminf(127.f, fmaxf(-127.f, rintf(xv / sx)));
      }
      Xs8[col * FXS_ROW + c] = (char)q;
    }
    for (int idx = tid; idx < 16384; idx += 256) {
      const int c = idx & 127, o = idx >> 7;
      const float s = scaleS[o];
      const float* wp = w + (size_t)(o0 + o) * 1152 + c * 9 + kh * 3;
#pragma unroll
      for (int kw = 0; kw < 3; ++kw) {
        const int q = (int)fminf(127.f, fmaxf(-127.f, rintf(wp[kw] / s)));
        As8[o * FAS_ROW + kw * 128 + c] = (char)q;
      }
    }
    __syncthreads();
    const int obase = wave * 32;
#pragma unroll
    for (int kw = 0; kw < 3; ++kw) {
#pragma unroll
      for (int c0 = 0; c0 < 128; c0 += 32) {
        long aop[2], bop[4];
#pragma unroll
        for (int t = 0; t < 2; ++t)
          aop[t] = *(const long*)(As8 + (obase + t * 16 + l16) * FAS_ROW + kw * 128 + c0 + quad * 8);
#pragma unroll
        for (int u = 0; u < 4; ++u)
          bop[u] = *(const long*)(Xs8 + (u * 16 + l16 + kw) * FXS_ROW + c0 + quad * 8);
#pragma unroll
        for (int t = 0; t < 2; ++t)
#pragma unroll
          for (int u = 0; u < 4; ++u)
            acc[t][u] = __builtin_amdgcn_mfma_i32_16x16x32_i8(aop[t], bop[u], acc[t][u], 0, 0, 0);
      }
    }
  }
#pragma unroll
  for (int t = 0; t < 2; ++t) {
#pragma unroll
    for (int u = 0; u < 4; ++u) {
#pragma unroll
      for (int r = 0; r < 4; ++r) {
        const int ol = wave * 32 + t * 16 + m_r[r];
        const int ow = u * 16 + n_r[r];
        if (ow < WW)
          out[(((size_t)b * OCH + o0 + ol) * HH + oh) * WW + ow] =
              (float)acc[t][u][r] * alphaS[ol] + biasS[ol];
      }
    }
  }
}

extern "C" void kernel_launch(void* const* d_in, const int* in_sizes, int n_in,
                              void* d_out, int out_size, void* d_ws, size_t ws_size,
                              hipStream_t stream) {
  const float *x = nullptr, *w = nullptr, *bias = nullptr, *sx = nullptr;
  for (int i = 0; i < n_in; ++i) {
    const int s = in_sizes[i];
    if (s == BATCH * CIN * HH * WW) x = (const float*)d_in[i];
    else if (s == OCH * CIN * 9)    w = (const float*)d_in[i];
    else if (s == OCH)              bias = (const float*)d_in[i];
    else if (s == 1)                sx = (const float*)d_in[i];
  }
  if (!x || !w || !bias || !sx) {
    x = (const float*)d_in[0]; w = (const float*)d_in[1];
    bias = (const float*)d_in[2]; sx = (const float*)d_in[3];
  }
  float* out = (float*)d_out;

  if (ws_size >= (size_t)WS_NEEDED) {
    unsigned int* qxp = (unsigned int*)d_ws;
    char* qwf = (char*)d_ws + QX_BYTES;
    float* alpha = (float*)((char*)d_ws + QX_BYTES + QW_BYTES);
    quant_w_kernel<<<OCH, 256, 0, stream>>>(w, sx, qwf, alpha);
    quant_x_kernel<<<BATCH * HH, 256, 0, stream>>>(x, sx, qxp);
    conv_kernel<<<dim3(BATCH * HH, 2), 256, 0, stream>>>(
        (const char*)qxp, qwf, alpha, bias, out);
  } else {
    conv_fused_kernel<<<dim3(BATCH * HH, 2), 256, 0, stream>>>(x, w, bias, sx, out);
  }
}

// Round 3
// 224.847 us; speedup vs baseline: 1.6025x; 1.0012x over previous
//
#include <hip/hip_runtime.h>

// Conv2d + BN int8 quantized, MI355X gfx950. Inputs fp32, output fp32.
// R8: R7's swizzle was 3-bit ((col&7)<<4) -> only 8 slots for 16 lanes ->
// 2-way conflict on EVERY b64 B-read (8.26M conflict cycles = 4/read, measured).
// Fix: 4-bit phase at 8B granularity. qxp byte j of row w holds channel
// j ^ (((w+1)&15)<<3); conv reads boff = (c04*32+quad*8) ^ (((l16+kw)&15)<<3).
// Each 16-lane quad group now hits 16 distinct even start-banks (1 lane each).
// Staging stays linear (global_load_lds width=16); permutation pre-applied at
// quant time (T2 both-sides rule). Everything else identical to R7.
// Host falls back to the proven R5 fused kernel if ws_size is too small.

#define BATCH 32
#define CIN   128
#define HH    56
#define WW    56
#define OCH   256

typedef __attribute__((ext_vector_type(4))) int int4v;

#define QX_BYTES (32 * 56 * 56 * 128)           // 12,845,056  qxp[b][h][w][c]
#define QW_BYTES (256 * 1152)                   // 294,912 (fragment-packed)
#define WS_NEEDED (QX_BYTES + QW_BYTES + 1024)

__device__ __forceinline__ void gload_lds16(const void* g, void* l) {
  __builtin_amdgcn_global_load_lds(
      (const __attribute__((address_space(1))) unsigned int*)g,
      (__attribute__((address_space(3))) unsigned int*)l, 16, 0, 0);
}

// ---------------- kernel 1: weight quantization + fragment pack ------------
// One block per output channel o. Output long index (same format as R6):
//   qwfL[og*4608 + ((r*4+c04)*2+t)*64 + l16*4+quad], og=o>>5, t=(o>>4)&1,
//   l16=o&15, holding channels c04*32+quad*8..+7 at tap r = kh*3+kw.
__global__ __launch_bounds__(256) void quant_w_kernel(
    const float* __restrict__ w, const float* __restrict__ sxp,
    char* __restrict__ qwf, float* __restrict__ alpha) {
  __shared__ float wf[1152];
  __shared__ float red[256];
  const int o = blockIdx.x;
  const int tid = threadIdx.x;
  const float* wrow = w + (size_t)o * 1152;
  float m = 0.f;
  for (int i = tid; i < 288; i += 256) {
    const float4 v = ((const float4*)wrow)[i];
    ((float4*)wf)[i] = v;
    m = fmaxf(m, fmaxf(fmaxf(fabsf(v.x), fabsf(v.y)),
                       fmaxf(fabsf(v.z), fabsf(v.w))));
  }
  red[tid] = m;
  __syncthreads();
  for (int s = 128; s > 0; s >>= 1) {
    if (tid < s) red[tid] = fmaxf(red[tid], red[tid + s]);
    __syncthreads();
  }
  const float sc = red[0] / 127.0f;   // max/QMAX, fp32, matches reference
  if (tid == 0) alpha[o] = sc * sxp[0];
  if (tid < 36) {
    const int r = tid >> 2, c04 = tid & 3;
    const int og = o >> 5, t = (o >> 4) & 1, l16 = o & 15;
    unsigned int* dst = (unsigned int*)(qwf + (size_t)og * 36864 +
                                        ((r * 4 + c04) * 2 + t) * 512 + l16 * 32);
#pragma unroll
    for (int g = 0; g < 8; ++g) {
      unsigned int pk = 0;
#pragma unroll
      for (int k = 0; k < 4; ++k) {
        const int c = c04 * 32 + g * 4 + k;
        const int q = (int)fminf(127.f, fmaxf(-127.f, rintf(wf[c * 9 + r] / sc)));
        pk |= ((unsigned int)(q & 255)) << (8 * k);
      }
      dst[g] = pk;
    }
  }
}

// ---------------- kernel 2: x quantization -> swizzled im2col rows ---------
// qxp byte ((b*56+h)*56 + w)*128 + j holds q(x[b][ j^(((w+1)&15)<<3) ][h][w]).
__global__ __launch_bounds__(256) void quant_x_kernel(
    const float* __restrict__ x, const float* __restrict__ sxp,
    unsigned int* __restrict__ qxp) {
  __shared__ char ldsA[128 * 60];   // [c][w] quantized bytes, stride 60
  const int row = blockIdx.x;       // b*56 + h
  const int b = row / 56, h = row % 56;
  const float sx = sxp[0];
  for (int i = threadIdx.x; i < 1792; i += 256) {
    const int c = i / 14, f = i % 14;
    const float4 v =
        *(const float4*)(x + (((size_t)b * 128 + c) * 56 + h) * 56 + 4 * f);
    unsigned int pk;
    pk  = (unsigned int)((int)fminf(127.f, fmaxf(-127.f, rintf(v.x / sx))) & 255);
    pk |= ((unsigned int)((int)fminf(127.f, fmaxf(-127.f, rintf(v.y / sx))) & 255)) << 8;
    pk |= ((unsigned int)((int)fminf(127.f, fmaxf(-127.f, rintf(v.z / sx))) & 255)) << 16;
    pk |= ((unsigned int)((int)fminf(127.f, fmaxf(-127.f, rintf(v.w / sx))) & 255)) << 24;
    *(unsigned int*)(ldsA + c * 60 + 4 * f) = pk;
  }
  __syncthreads();
  unsigned int* orow = qxp + (size_t)row * 56 * 32;
  for (int i = threadIdx.x; i < 1792; i += 256) {
    const int w = i >> 5, jd = i & 31;
    // byte p of row w holds channel p ^ (((w+1)&15)<<3); dword-level: ph<<1
    const int c0 = (jd ^ (((w + 1) & 15) << 1)) << 2;  // channel base (4-run)
    unsigned int pk = 0;
#pragma unroll
    for (int k = 0; k < 4; ++k)
      pk |= ((unsigned int)(unsigned char)ldsA[(c0 + k) * 60 + w]) << (8 * k);
    orow[i] = pk;
  }
}

// ---------------- kernel 3: conv (i8 MFMA, weights from L2) ----------------
#define XSLAB 8448                  // 66 cols * 128B, contiguous (no pad)

__global__ __launch_bounds__(256, 6) void conv_kernel(
    const char* __restrict__ qxp, const char* __restrict__ qwf,
    const float* __restrict__ alpha, const float* __restrict__ bias,
    float* __restrict__ out) {
  __shared__ __attribute__((aligned(16))) char Xs8[3 * XSLAB];  // 25,344 B

  const int bi = blockIdx.x;
  const int b  = bi / 56;
  const int oh = bi % 56;
  const int o0 = blockIdx.y * 128;
  const int tid = threadIdx.x;
  const int wave = tid >> 6, lane = tid & 63;
  const int l16 = lane & 15, quad = lane >> 4;

  // in-block MFMA C/D layout probe (verified working since R5)
  int m_r[4], n_r[4];
  {
    int4v zz = {0, 0, 0, 0};
    long a1 = 0, b1 = 0, a2 = 0, b2 = 0;
    if (quad == 0) {
      a1 = 1L;               // A = delta(k=0)
      b1 = (long)(l16 + 1);  // B[0][n] = n+1
      a2 = (long)(l16 + 1);  // A[m][0] = m+1
      b2 = 1L;               // B = delta(k=0)
    }
    int4v d1 = __builtin_amdgcn_mfma_i32_16x16x32_i8(a1, b1, zz, 0, 0, 0);
    int4v d2 = __builtin_amdgcn_mfma_i32_16x16x32_i8(a2, b2, zz, 0, 0, 0);
#pragma unroll
    for (int r = 0; r < 4; ++r) {
      n_r[r] = (d1[r] - 1) & 15;
      m_r[r] = (d2[r] - 1) & 15;
    }
  }

  // ---- stage 3 input rows: contiguous async copies + small zero fills ----
  for (int kh = 0; kh < 3; ++kh) {
    const int ih = oh - 1 + kh;
    char* slab = Xs8 + kh * XSLAB;
    if (ih >= 0 && ih < HH) {
      const char* src = qxp + ((size_t)b * 56 + ih) * 7168;
      for (int i = tid; i < 448; i += 256)
        gload_lds16(src + i * 16, slab + 128 + i * 16);   // cols 1..56
      for (int i = tid; i < 320; i += 256) {              // zero cols 0,57..65
        const int cg = i >> 5, dw = i & 31;
        const int col = (cg == 0) ? 0 : 56 + cg;
        ((unsigned int*)slab)[col * 32 + dw] = 0u;
      }
    } else {
      for (int i = tid; i < 2112; i += 256) ((unsigned int*)slab)[i] = 0u;
    }
  }

  int4v acc[2][4];
#pragma unroll
  for (int t = 0; t < 2; ++t)
#pragma unroll
    for (int u = 0; u < 4; ++u) acc[t][u] = (int4v){0, 0, 0, 0};

  __syncthreads();   // drains vmcnt (global_load_lds) + lgkm (zero stores)

  // A-operands streamed straight from L2, fragment-packed & coalesced.
  const long* wbase = (const long*)qwf +
      (size_t)(blockIdx.y * 4 + wave) * 4608 + (l16 * 4 + quad);

#pragma unroll
  for (int kh = 0; kh < 3; ++kh) {
    const char* Xk = Xs8 + kh * XSLAB;
#pragma unroll
    for (int kw = 0; kw < 3; ++kw) {
      const int ph = ((l16 + kw) & 15) << 3;  // 4-bit row-phase, u-invariant
#pragma unroll
      for (int c04 = 0; c04 < 4; ++c04) {
        const int fi = ((kh * 3 + kw) * 4 + c04) * 2;
        const long aop0 = wbase[(size_t)fi * 64];
        const long aop1 = wbase[(size_t)fi * 64 + 64];
        const int boff = (c04 * 32 + quad * 8) ^ ph;
        long bop[4];
#pragma unroll
        for (int u = 0; u < 4; ++u)
          bop[u] = *(const long*)(Xk + (u * 16 + l16 + kw) * 128 + boff);
#pragma unroll
        for (int u = 0; u < 4; ++u) {
          acc[0][u] = __builtin_amdgcn_mfma_i32_16x16x32_i8(
              aop0, bop[u], acc[0][u], 0, 0, 0);
          acc[1][u] = __builtin_amdgcn_mfma_i32_16x16x32_i8(
              aop1, bop[u], acc[1][u], 0, 0, 0);
        }
      }
    }
  }

#pragma unroll
  for (int t = 0; t < 2; ++t) {
#pragma unroll
    for (int u = 0; u < 4; ++u) {
#pragma unroll
      for (int r = 0; r < 4; ++r) {
        const int ol = wave * 32 + t * 16 + m_r[r];
        const int ow = u * 16 + n_r[r];
        if (ow < WW) {
          const int oo = o0 + ol;
          out[(((size_t)b * OCH + oo) * HH + oh) * WW + ow] =
              (float)acc[t][u][r] * alpha[oo] + bias[oo];
        }
      }
    }
  }
}

// ---------------- fallback: R5's proven fused kernel (ws-free) -------------
#define FAS_ROW 392
#define FXS_ROW 136
#define FLDS_XS (128 * FAS_ROW)
#define FLDS_SC (FLDS_XS + 66 * FXS_ROW)
#define FLDS_AL (FLDS_SC + 512)
#define FLDS_BI (FLDS_AL + 512)
#define FLDS_RED (FLDS_BI + 512)
#define FLDS_TOT (FLDS_RED + 1024)

__global__ __launch_bounds__(256) void conv_fused_kernel(
    const float* __restrict__ x, const float* __restrict__ w,
    const float* __restrict__ bias, const float* __restrict__ sxp,
    float* __restrict__ out) {
  __shared__ __attribute__((aligned(16))) char lds[FLDS_TOT];
  char* As8 = lds;
  char* Xs8 = lds + FLDS_XS;
  float* scaleS = (float*)(lds + FLDS_SC);
  float* alphaS = (float*)(lds + FLDS_AL);
  float* biasS  = (float*)(lds + FLDS_BI);
  float* red    = (float*)(lds + FLDS_RED);

  const int bi = blockIdx.x;
  const int b  = bi / 56;
  const int oh = bi % 56;
  const int o0 = blockIdx.y * 128;
  const int tid = threadIdx.x;
  const int wave = tid >> 6, lane = tid & 63;
  const int l16 = lane & 15, quad = lane >> 4;
  const float sx = sxp[0];

  int m_r[4], n_r[4];
  {
    int4v zz = {0, 0, 0, 0};
    long a1 = 0, b1 = 0, a2 = 0, b2 = 0;
    if (quad == 0) { a1 = 1L; b1 = (long)(l16 + 1); a2 = (long)(l16 + 1); b2 = 1L; }
    int4v d1 = __builtin_amdgcn_mfma_i32_16x16x32_i8(a1, b1, zz, 0, 0, 0);
    int4v d2 = __builtin_amdgcn_mfma_i32_16x16x32_i8(a2, b2, zz, 0, 0, 0);
#pragma unroll
    for (int r = 0; r < 4; ++r) { n_r[r] = (d1[r] - 1) & 15; m_r[r] = (d2[r] - 1) & 15; }
  }
  {
    const int o = tid >> 1, half = tid & 1;
    const float4* p = (const float4*)(w + (size_t)(o0 + o) * 1152 + half * 576);
    float m = 0.f;
#pragma unroll 4
    for (int i = 0; i < 144; ++i) {
      const float4 v = p[i];
      m = fmaxf(m, fmaxf(fmaxf(fabsf(v.x), fabsf(v.y)), fmaxf(fabsf(v.z), fabsf(v.w))));
    }
    red[tid] = m;
  }
  __syncthreads();
  {
    const int o = tid >> 1;
    if ((tid & 1) == 0) {
      const float sc = fmaxf(red[2 * o], red[2 * o + 1]) / 127.0f;
      scaleS[o] = sc; alphaS[o] = sc * sx; biasS[o] = bias[o0 + o];
    }
  }
  int4v acc[2][4];
#pragma unroll
  for (int t = 0; t < 2; ++t)
#pragma unroll
    for (int u = 0; u < 4; ++u) acc[t][u] = (int4v){0, 0, 0, 0};

  for (int kh = 0; kh < 3; ++kh) {
    const int ih = oh - 1 + kh;
    const bool row_ok = (ih >= 0) && (ih < HH);
    __syncthreads();
    for (int idx = tid; idx < 66 * 128; idx += 256) {
      const int col = idx % 66, c = idx / 66, iw = col - 1;
      int q = 0;
      if (row_ok && iw >= 0 && iw < WW) {
        const float xv = x[(((size_t)b * CIN + c) * HH + ih) * WW + iw];
        q = (int)fminf(127.f, fmaxf(-127.f, rintf(xv / sx)));
      }
      Xs8[col * FXS_ROW + c] = (char)q;
    }
    for (int idx = tid; idx < 16384; idx += 256) {
      const int c = idx & 127, o = idx >> 7;
      const float s = scaleS[o];
      const float* wp = w + (size_t)(o0 + o) * 1152 + c * 9 + kh * 3;
#pragma unroll
      for (int kw = 0; kw < 3; ++kw) {
        const int q = (int)fminf(127.f, fmaxf(-127.f, rintf(wp[kw] / s)));
        As8[o * FAS_ROW + kw * 128 + c] = (char)q;
      }
    }
    __syncthreads();
    const int obase = wave * 32;
#pragma unroll
    for (int kw = 0; kw < 3; ++kw) {
#pragma unroll
      for (int c0 = 0; c0 < 128; c0 += 32) {
        long aop[2], bop[4];
#pragma unroll
        for (int t = 0; t < 2; ++t)
          aop[t] = *(const long*)(As8 + (obase + t * 16 + l16) * FAS_ROW + kw * 128 + c0 + quad * 8);
#pragma unroll
        for (int u = 0; u < 4; ++u)
          bop[u] = *(const long*)(Xs8 + (u * 16 + l16 + kw) * FXS_ROW + c0 + quad * 8);
#pragma unroll
        for (int t = 0; t < 2; ++t)
#pragma unroll
          for (int u = 0; u < 4; ++u)
            acc[t][u] = __builtin_amdgcn_mfma_i32_16x16x32_i8(aop[t], bop[u], acc[t][u], 0, 0, 0);
      }
    }
  }
#pragma unroll
  for (int t = 0; t < 2; ++t) {
#pragma unroll
    for (int u = 0; u < 4; ++u) {
#pragma unroll
      for (int r = 0; r < 4; ++r) {
        const int ol = wave * 32 + t * 16 + m_r[r];
        const int ow = u * 16 + n_r[r];
        if (ow < WW)
          out[(((size_t)b * OCH + o0 + ol) * HH + oh) * WW + ow] =
              (float)acc[t][u][r] * alphaS[ol] + biasS[ol];
      }
    }
  }
}

extern "C" void kernel_launch(void* const* d_in, const int* in_sizes, int n_in,
                              void* d_out, int out_size, void* d_ws, size_t ws_size,
                              hipStream_t stream) {
  const float *x = nullptr, *w = nullptr, *bias = nullptr, *sx = nullptr;
  for (int i = 0; i < n_in; ++i) {
    const int s = in_sizes[i];
    if (s == BATCH * CIN * HH * WW) x = (const float*)d_in[i];
    else if (s == OCH * CIN * 9)    w = (const float*)d_in[i];
    else if (s == OCH)              bias = (const float*)d_in[i];
    else if (s == 1)                sx = (const float*)d_in[i];
  }
  if (!x || !w || !bias || !sx) {
    x = (const float*)d_in[0]; w = (const float*)d_in[1];
    bias = (const float*)d_in[2]; sx = (const float*)d_in[3];
  }
  float* out = (float*)d_out;

  if (ws_size >= (size_t)WS_NEEDED) {
    unsigned int* qxp = (unsigned int*)d_ws;
    char* qwf = (char*)d_ws + QX_BYTES;
    float* alpha = (float*)((char*)d_ws + QX_BYTES + QW_BYTES);
    quant_w_kernel<<<OCH, 256, 0, stream>>>(w, sx, qwf, alpha);
    quant_x_kernel<<<BATCH * HH, 256, 0, stream>>>(x, sx, qxp);
    conv_kernel<<<dim3(BATCH * HH, 2), 256, 0, stream>>>(
        (const char*)qxp, qwf, alpha, bias, out);
  } else {
    conv_fused_kernel<<<dim3(BATCH * HH, 2), 256, 0, stream>>>(x, w, bias, sx, out);
  }
}

// Round 4
// 196.946 us; speedup vs baseline: 1.8296x; 1.1417x over previous
//
#include <hip/hip_runtime.h>

// Conv2d + BN int8 quantized, MI355X gfx950. Inputs fp32, output fp32.
// R9: R8 fixed bank conflicts (8.26M->0) but time barely moved: the real costs
// are (a) cross-XCD scatter: qxp rows fetched ~6x from HBM (FETCH 68MB vs
// 12.8MB ideal) and oh/oh+1 output boundary lines RMW'd on different XCDs
// (WRITE 160MB vs 103MB ideal); (b) A-operand L2 latency: 36 unrolled K-steps
// each stall ~300cyc on just-in-time aop loads (VGPR=40 = no prefetch depth).
// Fixes:
//   - chunked XCD swizzle (bijective, 3584=8*448): XCD c owns bi in
//     [c*224,(c+1)*224) for both y-halves -> row reuse + write merge in-L2.
//   - qwf repacked so t=0/1 fragments form one long2 (16B/lane, dwordx4),
//     double-buffered one (kh,kw)-group ahead in registers (static indices).
// Host falls back to the proven R5 fused kernel if ws_size is too small.

#define BATCH 32
#define CIN   128
#define HH    56
#define WW    56
#define OCH   256

typedef __attribute__((ext_vector_type(4))) int int4v;
typedef __attribute__((ext_vector_type(2))) long longx2;

#define QX_BYTES (32 * 56 * 56 * 128)           // 12,845,056  qxp[b][h][w][c]
#define QW_BYTES (256 * 1152)                   // 294,912 (fragment-packed)
#define WS_NEEDED (QX_BYTES + QW_BYTES + 1024)

__device__ __forceinline__ void gload_lds16(const void* g, void* l) {
  __builtin_amdgcn_global_load_lds(
      (const __attribute__((address_space(1))) unsigned int*)g,
      (__attribute__((address_space(3))) unsigned int*)l, 16, 0, 0);
}

// ---------------- kernel 1: weight quantization + fragment pack ------------
// One block per output channel o. NEW layout (t-pair merged into long2):
//   byte ((og*36 + r*4 + c04)*128 + (l16*4+quad)*2 + t)*8 + (half*4+k)
//   holds channel c04*32+quad*8+half*4+k of o = og*32+t*16+l16 at tap r.
// Conv lane (l16,quad) loads long2 at longx2 index (r*4+c04)*64 + l16*4+quad:
//   [0] = t=0 operand, [1] = t=1 operand; wave chunk = contiguous 1KB.
__global__ __launch_bounds__(256) void quant_w_kernel(
    const float* __restrict__ w, const float* __restrict__ sxp,
    char* __restrict__ qwf, float* __restrict__ alpha) {
  __shared__ float wf[1152];
  __shared__ float red[256];
  const int o = blockIdx.x;
  const int tid = threadIdx.x;
  const float* wrow = w + (size_t)o * 1152;
  float m = 0.f;
  for (int i = tid; i < 288; i += 256) {
    const float4 v = ((const float4*)wrow)[i];
    ((float4*)wf)[i] = v;
    m = fmaxf(m, fmaxf(fmaxf(fabsf(v.x), fabsf(v.y)),
                       fmaxf(fabsf(v.z), fabsf(v.w))));
  }
  red[tid] = m;
  __syncthreads();
  for (int s = 128; s > 0; s >>= 1) {
    if (tid < s) red[tid] = fmaxf(red[tid], red[tid + s]);
    __syncthreads();
  }
  const float sc = red[0] / 127.0f;   // max/QMAX, fp32, matches reference
  if (tid == 0) alpha[o] = sc * sxp[0];
  if (tid < 36) {
    const int r = tid >> 2, c04 = tid & 3;
    const int og = o >> 5, t = (o >> 4) & 1, l16 = o & 15;
    unsigned int* base = (unsigned int*)(qwf + (size_t)og * 36864 +
                                         (size_t)(r * 4 + c04) * 1024);
#pragma unroll
    for (int quad = 0; quad < 4; ++quad) {
#pragma unroll
      for (int half = 0; half < 2; ++half) {
        unsigned int pk = 0;
#pragma unroll
        for (int k = 0; k < 4; ++k) {
          const int c = c04 * 32 + quad * 8 + half * 4 + k;
          const int q =
              (int)fminf(127.f, fmaxf(-127.f, rintf(wf[c * 9 + r] / sc)));
          pk |= ((unsigned int)(q & 255)) << (8 * k);
        }
        base[(l16 * 4 + quad) * 4 + t * 2 + half] = pk;
      }
    }
  }
}

// ---------------- kernel 2: x quantization -> swizzled im2col rows ---------
// qxp byte ((b*56+h)*56 + w)*128 + j holds q(x[b][ j^(((w+1)&15)<<3) ][h][w]).
__global__ __launch_bounds__(256) void quant_x_kernel(
    const float* __restrict__ x, const float* __restrict__ sxp,
    unsigned int* __restrict__ qxp) {
  __shared__ char ldsA[128 * 60];   // [c][w] quantized bytes, stride 60
  const int row = blockIdx.x;       // b*56 + h
  const int b = row / 56, h = row % 56;
  const float sx = sxp[0];
  for (int i = threadIdx.x; i < 1792; i += 256) {
    const int c = i / 14, f = i % 14;
    const float4 v =
        *(const float4*)(x + (((size_t)b * 128 + c) * 56 + h) * 56 + 4 * f);
    unsigned int pk;
    pk  = (unsigned int)((int)fminf(127.f, fmaxf(-127.f, rintf(v.x / sx))) & 255);
    pk |= ((unsigned int)((int)fminf(127.f, fmaxf(-127.f, rintf(v.y / sx))) & 255)) << 8;
    pk |= ((unsigned int)((int)fminf(127.f, fmaxf(-127.f, rintf(v.z / sx))) & 255)) << 16;
    pk |= ((unsigned int)((int)fminf(127.f, fmaxf(-127.f, rintf(v.w / sx))) & 255)) << 24;
    *(unsigned int*)(ldsA + c * 60 + 4 * f) = pk;
  }
  __syncthreads();
  unsigned int* orow = qxp + (size_t)row * 56 * 32;
  for (int i = threadIdx.x; i < 1792; i += 256) {
    const int w = i >> 5, jd = i & 31;
    // byte p of row w holds channel p ^ (((w+1)&15)<<3); dword-level: ph<<1
    const int c0 = (jd ^ (((w + 1) & 15) << 1)) << 2;  // channel base (4-run)
    unsigned int pk = 0;
#pragma unroll
    for (int k = 0; k < 4; ++k)
      pk |= ((unsigned int)(unsigned char)ldsA[(c0 + k) * 60 + w]) << (8 * k);
    orow[i] = pk;
  }
}

// ---------------- kernel 3: conv (i8 MFMA, weights from L2) ----------------
#define XSLAB 8448                  // 66 cols * 128B, contiguous (no pad)

__global__ __launch_bounds__(256, 6) void conv_kernel(
    const char* __restrict__ qxp, const char* __restrict__ qwf,
    const float* __restrict__ alpha, const float* __restrict__ bias,
    float* __restrict__ out) {
  __shared__ __attribute__((aligned(16))) char Xs8[3 * XSLAB];  // 25,344 B

  // chunked XCD swizzle: XCD (id&7) owns bi in [xcd*224, xcd*224+224), both y
  const int id = blockIdx.x;        // 0..3583, grid is 1-D
  const int xcd = id & 7;
  int kk = id >> 3;                 // 0..447
  const int yy = (kk >= 224) ? 1 : 0;
  kk -= yy * 224;                   // 0..223
  const int bi = xcd * 224 + kk;
  const int b  = bi / 56;
  const int oh = bi % 56;
  const int o0 = yy * 128;
  const int tid = threadIdx.x;
  const int wave = tid >> 6, lane = tid & 63;
  const int l16 = lane & 15, quad = lane >> 4;

  // in-block MFMA C/D layout probe (verified working since R5)
  int m_r[4], n_r[4];
  {
    int4v zz = {0, 0, 0, 0};
    long a1 = 0, b1 = 0, a2 = 0, b2 = 0;
    if (quad == 0) {
      a1 = 1L;               // A = delta(k=0)
      b1 = (long)(l16 + 1);  // B[0][n] = n+1
      a2 = (long)(l16 + 1);  // A[m][0] = m+1
      b2 = 1L;               // B = delta(k=0)
    }
    int4v d1 = __builtin_amdgcn_mfma_i32_16x16x32_i8(a1, b1, zz, 0, 0, 0);
    int4v d2 = __builtin_amdgcn_mfma_i32_16x16x32_i8(a2, b2, zz, 0, 0, 0);
#pragma unroll
    for (int r = 0; r < 4; ++r) {
      n_r[r] = (d1[r] - 1) & 15;
      m_r[r] = (d2[r] - 1) & 15;
    }
  }

  // A-operand base: per-lane long2 (t=0,t=1 fragments), wave chunk = 1KB.
  const longx2* wb2 = (const longx2*)(qwf + (size_t)(yy * 4 + wave) * 36864) +
                      (l16 * 4 + quad);
  longx2 ap[2][4];
#pragma unroll
  for (int c04 = 0; c04 < 4; ++c04) ap[0][c04] = wb2[(size_t)c04 * 64];

  // ---- stage 3 input rows: contiguous async copies + small zero fills ----
  for (int kh = 0; kh < 3; ++kh) {
    const int ih = oh - 1 + kh;
    char* slab = Xs8 + kh * XSLAB;
    if (ih >= 0 && ih < HH) {
      const char* src = qxp + ((size_t)b * 56 + ih) * 7168;
      for (int i = tid; i < 448; i += 256)
        gload_lds16(src + i * 16, slab + 128 + i * 16);   // cols 1..56
      for (int i = tid; i < 320; i += 256) {              // zero cols 0,57..65
        const int cg = i >> 5, dw = i & 31;
        const int col = (cg == 0) ? 0 : 56 + cg;
        ((unsigned int*)slab)[col * 32 + dw] = 0u;
      }
    } else {
      for (int i = tid; i < 2112; i += 256) ((unsigned int*)slab)[i] = 0u;
    }
  }

  int4v acc[2][4];
#pragma unroll
  for (int t = 0; t < 2; ++t)
#pragma unroll
    for (int u = 0; u < 4; ++u) acc[t][u] = (int4v){0, 0, 0, 0};

  __syncthreads();   // drains vmcnt (global_load_lds + ap[0]) + lgkm

  // 9 (kh,kw)-groups, A double-buffered one full group ahead (static idx).
#pragma unroll
  for (int g = 0; g < 9; ++g) {
    const int kh = g / 3, kw = g % 3;
    if (g < 8) {
#pragma unroll
      for (int c04 = 0; c04 < 4; ++c04)
        ap[(g + 1) & 1][c04] = wb2[(size_t)((g + 1) * 4 + c04) * 64];
    }
    const char* Xk = Xs8 + kh * XSLAB;
    const int ph = ((l16 + kw) & 15) << 3;  // 4-bit row-phase, u-invariant
#pragma unroll
    for (int c04 = 0; c04 < 4; ++c04) {
      const int boff = (c04 * 32 + quad * 8) ^ ph;
      long bop[4];
#pragma unroll
      for (int u = 0; u < 4; ++u)
        bop[u] = *(const long*)(Xk + (u * 16 + l16 + kw) * 128 + boff);
#pragma unroll
      for (int u = 0; u < 4; ++u) {
        acc[0][u] = __builtin_amdgcn_mfma_i32_16x16x32_i8(
            ap[g & 1][c04][0], bop[u], acc[0][u], 0, 0, 0);
        acc[1][u] = __builtin_amdgcn_mfma_i32_16x16x32_i8(
            ap[g & 1][c04][1], bop[u], acc[1][u], 0, 0, 0);
      }
    }
  }

#pragma unroll
  for (int t = 0; t < 2; ++t) {
#pragma unroll
    for (int u = 0; u < 4; ++u) {
#pragma unroll
      for (int r = 0; r < 4; ++r) {
        const int ol = wave * 32 + t * 16 + m_r[r];
        const int ow = u * 16 + n_r[r];
        if (ow < WW) {
          const int oo = o0 + ol;
          out[(((size_t)b * OCH + oo) * HH + oh) * WW + ow] =
              (float)acc[t][u][r] * alpha[oo] + bias[oo];
        }
      }
    }
  }
}

// ---------------- fallback: R5's proven fused kernel (ws-free) -------------
#define FAS_ROW 392
#define FXS_ROW 136
#define FLDS_XS (128 * FAS_ROW)
#define FLDS_SC (FLDS_XS + 66 * FXS_ROW)
#define FLDS_AL (FLDS_SC + 512)
#define FLDS_BI (FLDS_AL + 512)
#define FLDS_RED (FLDS_BI + 512)
#define FLDS_TOT (FLDS_RED + 1024)

__global__ __launch_bounds__(256) void conv_fused_kernel(
    const float* __restrict__ x, const float* __restrict__ w,
    const float* __restrict__ bias, const float* __restrict__ sxp,
    float* __restrict__ out) {
  __shared__ __attribute__((aligned(16))) char lds[FLDS_TOT];
  char* As8 = lds;
  char* Xs8 = lds + FLDS_XS;
  float* scaleS = (float*)(lds + FLDS_SC);
  float* alphaS = (float*)(lds + FLDS_AL);
  float* biasS  = (float*)(lds + FLDS_BI);
  float* red    = (float*)(lds + FLDS_RED);

  const int bi = blockIdx.x;
  const int b  = bi / 56;
  const int oh = bi % 56;
  const int o0 = blockIdx.y * 128;
  const int tid = threadIdx.x;
  const int wave = tid >> 6, lane = tid & 63;
  const int l16 = lane & 15, quad = lane >> 4;
  const float sx = sxp[0];

  int m_r[4], n_r[4];
  {
    int4v zz = {0, 0, 0, 0};
    long a1 = 0, b1 = 0, a2 = 0, b2 = 0;
    if (quad == 0) { a1 = 1L; b1 = (long)(l16 + 1); a2 = (long)(l16 + 1); b2 = 1L; }
    int4v d1 = __builtin_amdgcn_mfma_i32_16x16x32_i8(a1, b1, zz, 0, 0, 0);
    int4v d2 = __builtin_amdgcn_mfma_i32_16x16x32_i8(a2, b2, zz, 0, 0, 0);
#pragma unroll
    for (int r = 0; r < 4; ++r) { n_r[r] = (d1[r] - 1) & 15; m_r[r] = (d2[r] - 1) & 15; }
  }
  {
    const int o = tid >> 1, half = tid & 1;
    const float4* p = (const float4*)(w + (size_t)(o0 + o) * 1152 + half * 576);
    float m = 0.f;
#pragma unroll 4
    for (int i = 0; i < 144; ++i) {
      const float4 v = p[i];
      m = fmaxf(m, fmaxf(fmaxf(fabsf(v.x), fabsf(v.y)), fmaxf(fabsf(v.z), fabsf(v.w))));
    }
    red[tid] = m;
  }
  __syncthreads();
  {
    const int o = tid >> 1;
    if ((tid & 1) == 0) {
      const float sc = fmaxf(red[2 * o], red[2 * o + 1]) / 127.0f;
      scaleS[o] = sc; alphaS[o] = sc * sx; biasS[o] = bias[o0 + o];
    }
  }
  int4v acc[2][4];
#pragma unroll
  for (int t = 0; t < 2; ++t)
#pragma unroll
    for (int u = 0; u < 4; ++u) acc[t][u] = (int4v){0, 0, 0, 0};

  for (int kh = 0; kh < 3; ++kh) {
    const int ih = oh - 1 + kh;
    const bool row_ok = (ih >= 0) && (ih < HH);
    __syncthreads();
    for (int idx = tid; idx < 66 * 128; idx += 256) {
      const int col = idx % 66, c = idx / 66, iw = col - 1;
      int q = 0;
      if (row_ok && iw >= 0 && iw < WW) {
        const float xv = x[(((size_t)b * CIN + c) * HH + ih) * WW + iw];
        q = (int)fminf(127.f, fmaxf(-127.f, rintf(xv / sx)));
      }
      Xs8[col * FXS_ROW + c] = (char)q;
    }
    for (int idx = tid; idx < 16384; idx += 256) {
      const int c = idx & 127, o = idx >> 7;
      const float s = scaleS[o];
      const float* wp = w + (size_t)(o0 + o) * 1152 + c * 9 + kh * 3;
#pragma unroll
      for (int kw = 0; kw < 3; ++kw) {
        const int q = (int)fminf(127.f, fmaxf(-127.f, rintf(wp[kw] / s)));
        As8[o * FAS_ROW + kw * 128 + c] = (char)q;
      }
    }
    __syncthreads();
    const int obase = wave * 32;
#pragma unroll
    for (int kw = 0; kw < 3; ++kw) {
#pragma unroll
      for (int c0 = 0; c0 < 128; c0 += 32) {
        long aop[2], bop[4];
#pragma unroll
        for (int t = 0; t < 2; ++t)
          aop[t] = *(const long*)(As8 + (obase + t * 16 + l16) * FAS_ROW + kw * 128 + c0 + quad * 8);
#pragma unroll
        for (int u = 0; u < 4; ++u)
          bop[u] = *(const long*)(Xs8 + (u * 16 + l16 + kw) * FXS_ROW + c0 + quad * 8);
#pragma unroll
        for (int t = 0; t < 2; ++t)
#pragma unroll
          for (int u = 0; u < 4; ++u)
            acc[t][u] = __builtin_amdgcn_mfma_i32_16x16x32_i8(aop[t], bop[u], acc[t][u], 0, 0, 0);
      }
    }
  }
#pragma unroll
  for (int t = 0; t < 2; ++t) {
#pragma unroll
    for (int u = 0; u < 4; ++u) {
#pragma unroll
      for (int r = 0; r < 4; ++r) {
        const int ol = wave * 32 + t * 16 + m_r[r];
        const int ow = u * 16 + n_r[r];
        if (ow < WW)
          out[(((size_t)b * OCH + o0 + ol) * HH + oh) * WW + ow] =
              (float)acc[t][u][r] * alphaS[ol] + biasS[ol];
      }
    }
  }
}

extern "C" void kernel_launch(void* const* d_in, const int* in_sizes, int n_in,
                              void* d_out, int out_size, void* d_ws, size_t ws_size,
                              hipStream_t stream) {
  const float *x = nullptr, *w = nullptr, *bias = nullptr, *sx = nullptr;
  for (int i = 0; i < n_in; ++i) {
    const int s = in_sizes[i];
    if (s == BATCH * CIN * HH * WW) x = (const float*)d_in[i];
    else if (s == OCH * CIN * 9)    w = (const float*)d_in[i];
    else if (s == OCH)              bias = (const float*)d_in[i];
    else if (s == 1)                sx = (const float*)d_in[i];
  }
  if (!x || !w || !bias || !sx) {
    x = (const float*)d_in[0]; w = (const float*)d_in[1];
    bias = (const float*)d_in[2]; sx = (const float*)d_in[3];
  }
  float* out = (float*)d_out;

  if (ws_size >= (size_t)WS_NEEDED) {
    unsigned int* qxp = (unsigned int*)d_ws;
    char* qwf = (char*)d_ws + QX_BYTES;
    float* alpha = (float*)((char*)d_ws + QX_BYTES + QW_BYTES);
    quant_w_kernel<<<OCH, 256, 0, stream>>>(w, sx, qwf, alpha);
    quant_x_kernel<<<BATCH * HH, 256, 0, stream>>>(x, sx, qxp);
    conv_kernel<<<BATCH * HH * 2, 256, 0, stream>>>(
        (const char*)qxp, qwf, alpha, bias, out);
  } else {
    conv_fused_kernel<<<dim3(BATCH * HH, 2), 256, 0, stream>>>(x, w, bias, sx, out);
  }
}